// Round 1
// baseline (27.378 us; speedup 1.0000x reference)
//
#include <hip/hip_runtime.h>

#define BB 2
#define NN 1024
#define FF 128
#define H1 64
#define H2 32

typedef __attribute__((ext_vector_type(8))) _Float16 half8;   // 8 f16 (4 VGPR)
typedef __attribute__((ext_vector_type(16))) float f32x16;    // 32x32 MFMA acc

// Kernel 1: pj[row,h] = x@W1[:F] ; pib[row,h] = x@W1[F:] + b1  (f16 outputs)
// Block 0 additionally packs W2 into fragment-ready W2T:
//   W2T[khi*32+m][e] = (f16)W2[khi*8+e][m]   (khi=0..7, m=0..31, e=0..7)
__global__ __launch_bounds__(256) void precompute_kernel(
    const float* __restrict__ x, const float* __restrict__ W1,
    const float* __restrict__ b1, const float* __restrict__ W2,
    _Float16* __restrict__ pj, _Float16* __restrict__ pib,
    _Float16* __restrict__ W2T)
{
    __shared__ float xs[4][FF];
    const int r = threadIdx.x >> 6;
    const int h = threadIdx.x & 63;
    const int row0 = blockIdx.x * 4;

    const float* xbase = x + (size_t)row0 * FF;
    for (int t = threadIdx.x; t < 4 * FF; t += 256)
        xs[t >> 7][t & 127] = xbase[t];
    __syncthreads();

    float accj = 0.f, acci = 0.f;
    #pragma unroll 8
    for (int k = 0; k < FF; ++k) {
        float xv = xs[r][k];
        accj = fmaf(xv, W1[k * H1 + h], accj);
        acci = fmaf(xv, W1[(FF + k) * H1 + h], acci);
    }
    size_t o = (size_t)(row0 + r) * H1 + h;
    pj[o]  = (_Float16)accj;
    pib[o] = (_Float16)(acci + b1[h]);

    if (blockIdx.x == 0) {   // fused W2 repack (no extra launch — round-11 lesson)
        const int m = threadIdx.x & 31, khi = threadIdx.x >> 5;
        half8 v;
        #pragma unroll
        for (int e = 0; e < 8; ++e)
            v[e] = (_Float16)W2[(khi * 8 + e) * H2 + m];
        *(half8*)(W2T + (khi * 32 + m) * 8) = v;
    }
}

// e = relu(a + b) in packed f16: 4x v_pk_add_f16 + 4x v_pk_max_f16
__device__ inline half8 addrelu8(half8 a, half8 b) {
    half8 s = a + b;
    const half8 z = {};
    return __builtin_elementwise_max(s, z);
}

// Kernel 2: one row-step = mfma_f32_32x32x16_f16 chain (K=64 via 4 MFMAs):
//   D = W2^T (A, M=32 h2) x E^T (B, N=32 edges = one i-row x 32 j-cols)
//   D: col = l&31 = edge(j), row = (reg&3)+8*(reg>>2)+4*(l>>5)  [m74/m101]
// This version: 16 single-row steps with a 1-row LDS lookahead (n0..n3) so
// ds_read latency + the 4-deep MFMA chain of row t overlap with row t+1's
// prefetch/addrelu. __launch_bounds__(256,4) pins VGPR<=128 so all 4
// blocks/CU are co-resident in one scheduling round.
__global__ __launch_bounds__(256, 4) void edge_kernel(
    const _Float16* __restrict__ pj, const _Float16* __restrict__ pib,
    const _Float16* __restrict__ W2T, const float* __restrict__ b2,
    const float* __restrict__ W3, const float* __restrict__ b3,
    float* __restrict__ out)
{
    __shared__ _Float16 plds[64][H1];   // 8 KB: block's 64 pib rows (f16)

    const int lane = threadIdx.x & 63;
    const int wv   = threadIdx.x >> 6;
    const int b  = blockIdx.z;
    const int i0 = blockIdx.y * 64;          // block: 64 i-rows (16 per wave)
    const int j0 = blockIdx.x * 32;          // 32 j-cols
    const int jn = lane & 31;                // m/n lane index (h2 row for A, j for B/D)
    const int hi = lane >> 5;                // k-group half

    // ---- async stage: wave's 16 pib rows (2 KB) into LDS, linear dest ----
    {
        const _Float16* src = pib + (size_t)(b * NN + i0 + wv * 16) * H1 + lane * 8;
        char* dst = (char*)&plds[wv * 16][0];
        #pragma unroll
        for (int r = 0; r < 2; ++r)
            __builtin_amdgcn_global_load_lds(
                (const __attribute__((address_space(1))) void*)(src + r * 512),
                (__attribute__((address_space(3))) void*)(dst + r * 1024),
                16, 0, 0);
    }

    // ---- per-wave init ----
    // A-frags: wa_c[e] = W2[16c + hi*8 + e][jn]  (4 b128 loads, fragment-ready)
    const half8 wa0 = *(const half8*)(W2T + ((0 + hi) * 32 + jn) * 8);
    const half8 wa1 = *(const half8*)(W2T + ((2 + hi) * 32 + jn) * 8);
    const half8 wa2 = *(const half8*)(W2T + ((4 + hi) * 32 + jn) * 8);
    const half8 wa3 = *(const half8*)(W2T + ((6 + hi) * 32 + jn) * 8);

    // B-frags (pj side), pinned: row j0+jn, k-slices 16c + hi*8
    const _Float16* pr = pj + (size_t)(b * NN + j0 + jn) * H1 + hi * 8;
    const half8 qj0 = *(const half8*)(pr);
    const half8 qj1 = *(const half8*)(pr + 16);
    const half8 qj2 = *(const half8*)(pr + 32);
    const half8 qj3 = *(const half8*)(pr + 48);

    f32x16 ci;
    float w3r[16];
    #pragma unroll
    for (int r = 0; r < 16; ++r) {           // D row mapping [m74/m101]
        const int row = (r & 3) + 8 * (r >> 2) + 4 * hi;
        ci[r]  = b2[row];
        w3r[r] = W3[row];
    }
    const float b3v = b3[0];

    __syncthreads();   // drains vmcnt (staging) then barrier

    const int srow = wv * 16;
    const _Float16* irbase = &plds[srow][0] + hi * 8;
    float* obase = out + (size_t)(b * NN + i0 + srow) * NN + j0 + jn;

    // prologue: load row 0 of this wave's 16
    half8 c0 = *(const half8*)(irbase);
    half8 c1 = *(const half8*)(irbase + 16);
    half8 c2 = *(const half8*)(irbase + 32);
    half8 c3 = *(const half8*)(irbase + 48);
    half8 n0, n1, n2, n3;
    float pe = 0.f;

    #pragma unroll 1
    for (int t = 0; t < 16; ++t) {
        if (t < 15) {                        // 1-row LDS lookahead
            const _Float16* ir = irbase + (t + 1) * H1;
            n0 = *(const half8*)(ir);
            n1 = *(const half8*)(ir + 16);
            n2 = *(const half8*)(ir + 32);
            n3 = *(const half8*)(ir + 48);
        }
        half8 e0 = addrelu8(qj0, c0);        // c* dies into e* (no reg growth)
        half8 e1 = addrelu8(qj1, c1);
        half8 e2 = addrelu8(qj2, c2);
        half8 e3 = addrelu8(qj3, c3);
        f32x16 d;
        d = __builtin_amdgcn_mfma_f32_32x32x16_f16(wa0, e0, ci, 0, 0, 0);
        d = __builtin_amdgcn_mfma_f32_32x32x16_f16(wa1, e1, d,  0, 0, 0);
        d = __builtin_amdgcn_mfma_f32_32x32x16_f16(wa2, e2, d,  0, 0, 0);
        d = __builtin_amdgcn_mfma_f32_32x32x16_f16(wa3, e3, d,  0, 0, 0);
        float p0 = 0.f, p1 = 0.f, p2 = 0.f, p3 = 0.f;   // 4 parallel chains
        #pragma unroll
        for (int r = 0; r < 4; ++r) {
            p0 = fmaf(fmaxf(d[r],      0.f), w3r[r],      p0);
            p1 = fmaf(fmaxf(d[4 + r],  0.f), w3r[4 + r],  p1);
            p2 = fmaf(fmaxf(d[8 + r],  0.f), w3r[8 + r],  p2);
            p3 = fmaf(fmaxf(d[12 + r], 0.f), w3r[12 + r], p3);
        }
        float p = (p0 + p1) + (p2 + p3);
        p += __shfl_xor(p, 32);              // lane-halves hold complementary rows
        if (t & 1) {                         // store a 2-row pair, full-wave
            float v = hi ? p : pe;           // hi half stores the odd row
            obase[(size_t)(t - 1 + hi) * NN] = v + b3v;
        } else {
            pe = p;
        }
        c0 = n0; c1 = n1; c2 = n2; c3 = n3;  // rotate pipeline regs
    }
}

extern "C" void kernel_launch(void* const* d_in, const int* in_sizes, int n_in,
                              void* d_out, int out_size, void* d_ws, size_t ws_size,
                              hipStream_t stream) {
    const float* x  = (const float*)d_in[0];
    // d_in[1] = adj (UNUSED by reference), d_in[2] = mask (UNUSED)
    const float* W1 = (const float*)d_in[3];
    const float* b1 = (const float*)d_in[4];
    const float* W2 = (const float*)d_in[5];
    const float* b2 = (const float*)d_in[6];
    const float* W3 = (const float*)d_in[7];
    const float* b3 = (const float*)d_in[8];
    float* out = (float*)d_out;

    _Float16* pj  = (_Float16*)d_ws;                    // B*N*H1 f16 = 256 KB
    _Float16* pib = pj + (size_t)BB * NN * H1;          // B*N*H1 f16 = 256 KB
    _Float16* W2T = pib + (size_t)BB * NN * H1;         // 64*32 f16 = 4 KB

    precompute_kernel<<<BB * NN / 4, 256, 0, stream>>>(x, W1, b1, W2, pj, pib, W2T);
    edge_kernel<<<dim3(NN / 32, NN / 64, BB), 256, 0, stream>>>(
        pj, pib, W2T, b2, W3, b3, out);
}

// Round 2
// 25.810 us; speedup vs baseline: 1.0608x; 1.0608x over previous
//
#include <hip/hip_runtime.h>

#define BB 2
#define NN 1024
#define FF 128
#define H1 64
#define H2 32

typedef __attribute__((ext_vector_type(8))) _Float16 half8;   // 8 f16 (4 VGPR)
typedef __attribute__((ext_vector_type(16))) float f32x16;    // 32x32 MFMA acc

// Kernel 1 (k-split): block = 4 rows, 256 threads, grid 512.
// Wave wv owns k-slice [32wv, 32wv+32): each W1 element is read ONCE per
// block (was 4x — once per row-wave), cutting per-CU L1 W1 traffic 4x
// (512KB -> 128KB/CU). Each thread accumulates partials for all 4 rows,
// then an 8KB LDS cross-wave reduction produces pj/pib (f16).
// Block 0 additionally packs W2 into fragment-ready W2T:
//   W2T[khi*32+m][e] = (f16)W2[khi*8+e][m]   (khi=0..7, m=0..31, e=0..7)
__global__ __launch_bounds__(256) void precompute_kernel(
    const float* __restrict__ x, const float* __restrict__ W1,
    const float* __restrict__ b1, const float* __restrict__ W2,
    _Float16* __restrict__ pj, _Float16* __restrict__ pib,
    _Float16* __restrict__ W2T)
{
    __shared__ float xs[4][FF];
    __shared__ float red[4][4][H1][2];   // [wave][row][h][{j,i}] = 8 KB
    const int h  = threadIdx.x & 63;
    const int wv = threadIdx.x >> 6;
    const int row0 = blockIdx.x * 4;

    const float* xbase = x + (size_t)row0 * FF;
    for (int t = threadIdx.x; t < 4 * FF; t += 256)
        xs[t >> 7][t & 127] = xbase[t];
    __syncthreads();

    float accj[4] = {}, acci[4] = {};
    const int k0 = wv * 32;
    #pragma unroll 8
    for (int kk = 0; kk < 32; ++kk) {
        const int k = k0 + kk;
        const float wj = W1[k * H1 + h];          // coalesced 256B, once/block
        const float wi = W1[(FF + k) * H1 + h];
        #pragma unroll
        for (int r = 0; r < 4; ++r) {
            const float xv = xs[r][k];            // wave-uniform -> broadcast
            accj[r] = fmaf(xv, wj, accj[r]);
            acci[r] = fmaf(xv, wi, acci[r]);
        }
    }
    #pragma unroll
    for (int r = 0; r < 4; ++r) {                 // float2 stores, 2-way=free
        red[wv][r][h][0] = accj[r];
        red[wv][r][h][1] = acci[r];
    }
    __syncthreads();

    // 512 outputs (r,h,c); thread handles o = tid and tid+256.
    #pragma unroll
    for (int half = 0; half < 2; ++half) {
        const int o = threadIdx.x + half * 256;
        const int c = o & 1, hh = (o >> 1) & 63, r = o >> 7;
        const float s = red[0][r][hh][c] + red[1][r][hh][c]
                      + red[2][r][hh][c] + red[3][r][hh][c];
        const size_t idx = (size_t)(row0 + r) * H1 + hh;
        if (c == 0) pj[idx]  = (_Float16)s;
        else        pib[idx] = (_Float16)(s + b1[hh]);
    }

    if (blockIdx.x == 0) {   // fused W2 repack (no extra launch — round-11 lesson)
        const int m = threadIdx.x & 31, khi = threadIdx.x >> 5;
        half8 v;
        #pragma unroll
        for (int e = 0; e < 8; ++e)
            v[e] = (_Float16)W2[(khi * 8 + e) * H2 + m];
        *(half8*)(W2T + (khi * 32 + m) * 8) = v;
    }
}

// e = relu(a + b) in packed f16: 4x v_pk_add_f16 + 4x v_pk_max_f16
__device__ inline half8 addrelu8(half8 a, half8 b) {
    half8 s = a + b;
    const half8 z = {};
    return __builtin_elementwise_max(s, z);
}

// Kernel 2: unchanged from round 1 (row-pipelined; R1 showed edge is
// insensitive to intra-wave scheduling — kept identical for attribution).
__global__ __launch_bounds__(256, 4) void edge_kernel(
    const _Float16* __restrict__ pj, const _Float16* __restrict__ pib,
    const _Float16* __restrict__ W2T, const float* __restrict__ b2,
    const float* __restrict__ W3, const float* __restrict__ b3,
    float* __restrict__ out)
{
    __shared__ _Float16 plds[64][H1];   // 8 KB: block's 64 pib rows (f16)

    const int lane = threadIdx.x & 63;
    const int wv   = threadIdx.x >> 6;
    const int b  = blockIdx.z;
    const int i0 = blockIdx.y * 64;          // block: 64 i-rows (16 per wave)
    const int j0 = blockIdx.x * 32;          // 32 j-cols
    const int jn = lane & 31;                // m/n lane index (h2 row for A, j for B/D)
    const int hi = lane >> 5;                // k-group half

    // ---- async stage: wave's 16 pib rows (2 KB) into LDS, linear dest ----
    {
        const _Float16* src = pib + (size_t)(b * NN + i0 + wv * 16) * H1 + lane * 8;
        char* dst = (char*)&plds[wv * 16][0];
        #pragma unroll
        for (int r = 0; r < 2; ++r)
            __builtin_amdgcn_global_load_lds(
                (const __attribute__((address_space(1))) void*)(src + r * 512),
                (__attribute__((address_space(3))) void*)(dst + r * 1024),
                16, 0, 0);
    }

    // ---- per-wave init ----
    // A-frags: wa_c[e] = W2[16c + hi*8 + e][jn]  (4 b128 loads, fragment-ready)
    const half8 wa0 = *(const half8*)(W2T + ((0 + hi) * 32 + jn) * 8);
    const half8 wa1 = *(const half8*)(W2T + ((2 + hi) * 32 + jn) * 8);
    const half8 wa2 = *(const half8*)(W2T + ((4 + hi) * 32 + jn) * 8);
    const half8 wa3 = *(const half8*)(W2T + ((6 + hi) * 32 + jn) * 8);

    // B-frags (pj side), pinned: row j0+jn, k-slices 16c + hi*8
    const _Float16* pr = pj + (size_t)(b * NN + j0 + jn) * H1 + hi * 8;
    const half8 qj0 = *(const half8*)(pr);
    const half8 qj1 = *(const half8*)(pr + 16);
    const half8 qj2 = *(const half8*)(pr + 32);
    const half8 qj3 = *(const half8*)(pr + 48);

    f32x16 ci;
    float w3r[16];
    #pragma unroll
    for (int r = 0; r < 16; ++r) {           // D row mapping [m74/m101]
        const int row = (r & 3) + 8 * (r >> 2) + 4 * hi;
        ci[r]  = b2[row];
        w3r[r] = W3[row];
    }
    const float b3v = b3[0];

    __syncthreads();   // drains vmcnt (staging) then barrier

    const int srow = wv * 16;
    const _Float16* irbase = &plds[srow][0] + hi * 8;
    float* obase = out + (size_t)(b * NN + i0 + srow) * NN + j0 + jn;

    // prologue: load row 0 of this wave's 16
    half8 c0 = *(const half8*)(irbase);
    half8 c1 = *(const half8*)(irbase + 16);
    half8 c2 = *(const half8*)(irbase + 32);
    half8 c3 = *(const half8*)(irbase + 48);
    half8 n0, n1, n2, n3;
    float pe = 0.f;

    #pragma unroll 1
    for (int t = 0; t < 16; ++t) {
        if (t < 15) {                        // 1-row LDS lookahead
            const _Float16* ir = irbase + (t + 1) * H1;
            n0 = *(const half8*)(ir);
            n1 = *(const half8*)(ir + 16);
            n2 = *(const half8*)(ir + 32);
            n3 = *(const half8*)(ir + 48);
        }
        half8 e0 = addrelu8(qj0, c0);        // c* dies into e* (no reg growth)
        half8 e1 = addrelu8(qj1, c1);
        half8 e2 = addrelu8(qj2, c2);
        half8 e3 = addrelu8(qj3, c3);
        f32x16 d;
        d = __builtin_amdgcn_mfma_f32_32x32x16_f16(wa0, e0, ci, 0, 0, 0);
        d = __builtin_amdgcn_mfma_f32_32x32x16_f16(wa1, e1, d,  0, 0, 0);
        d = __builtin_amdgcn_mfma_f32_32x32x16_f16(wa2, e2, d,  0, 0, 0);
        d = __builtin_amdgcn_mfma_f32_32x32x16_f16(wa3, e3, d,  0, 0, 0);
        float p0 = 0.f, p1 = 0.f, p2 = 0.f, p3 = 0.f;   // 4 parallel chains
        #pragma unroll
        for (int r = 0; r < 4; ++r) {
            p0 = fmaf(fmaxf(d[r],      0.f), w3r[r],      p0);
            p1 = fmaf(fmaxf(d[4 + r],  0.f), w3r[4 + r],  p1);
            p2 = fmaf(fmaxf(d[8 + r],  0.f), w3r[8 + r],  p2);
            p3 = fmaf(fmaxf(d[12 + r], 0.f), w3r[12 + r], p3);
        }
        float p = (p0 + p1) + (p2 + p3);
        p += __shfl_xor(p, 32);              // lane-halves hold complementary rows
        if (t & 1) {                         // store a 2-row pair, full-wave
            float v = hi ? p : pe;           // hi half stores the odd row
            obase[(size_t)(t - 1 + hi) * NN] = v + b3v;
        } else {
            pe = p;
        }
        c0 = n0; c1 = n1; c2 = n2; c3 = n3;  // rotate pipeline regs
    }
}

extern "C" void kernel_launch(void* const* d_in, const int* in_sizes, int n_in,
                              void* d_out, int out_size, void* d_ws, size_t ws_size,
                              hipStream_t stream) {
    const float* x  = (const float*)d_in[0];
    // d_in[1] = adj (UNUSED by reference), d_in[2] = mask (UNUSED)
    const float* W1 = (const float*)d_in[3];
    const float* b1 = (const float*)d_in[4];
    const float* W2 = (const float*)d_in[5];
    const float* b2 = (const float*)d_in[6];
    const float* W3 = (const float*)d_in[7];
    const float* b3 = (const float*)d_in[8];
    float* out = (float*)d_out;

    _Float16* pj  = (_Float16*)d_ws;                    // B*N*H1 f16 = 256 KB
    _Float16* pib = pj + (size_t)BB * NN * H1;          // B*N*H1 f16 = 256 KB
    _Float16* W2T = pib + (size_t)BB * NN * H1;         // 64*32 f16 = 4 KB

    precompute_kernel<<<BB * NN / 4, 256, 0, stream>>>(x, W1, b1, W2, pj, pib, W2T);
    edge_kernel<<<dim3(NN / 32, NN / 64, BB), 256, 0, stream>>>(
        pj, pib, W2T, b2, W3, b3, out);
}